// Round 25
// baseline (96.551 us; speedup 1.0000x reference)
//
#include <hip/hip_runtime.h>
#include <hip/hip_fp16.h>

// LGA2 fused: out = LGA(LGA(x,f),f), radius=2 (25 taps), fp32 in/out.
// x: [N=2, C=64, H=256, W=512], f: [N, 25, H, W], out like x.
//
// R25 = R24 (68.6us, passed) with ONE parameter change: CPB=8 -> grid
// 9x22x16 = 3168 blocks (12.4/CU). Mechanism: at CPB=32 the grid is 792 =
// 3.09 blocks/CU -- static imbalance (some CUs run a 4th block while the
// rest idle) ~ matches the stuck 25% OccupancyPercent. Finer-grained work
// lets dynamic scheduling balance: tail <= 1 block ~ 8%. Cost: filter
// traffic x4 (FETCH ~122 -> ~210MB, measured ~1.3us/47MB) + startup x4.
//
// R24 structure: channel-pair packing (f16 halves = same pixel, chans
// c/c+1), op_sel filter broadcast, 4 channels (2 pairs) per phase with two
// independent PASS2 chains, 2 lgkm barriers per 4 channels, staggered
// 4-buffer prefetch rotation. Tile: temp 16x64, out 12x60, x 20x68. USH=76.

typedef __fp16 h2v __attribute__((ext_vector_type(2)));

#define OH 12
#define OW 60
#define USH 76

__device__ __forceinline__ unsigned pkh(float a, float b) {
    union { h2v h; unsigned u; } c;
    c.h = __builtin_amdgcn_cvt_pkrtz(a, b);
    return c.u;
}

// acc.h[ch] += fv.LO * xv.h[ch]  (filter lo-half broadcast to both channels)
#define PKFL(ac, fv, xv) \
    asm("v_pk_fma_f16 %0, %1, %2, %0 op_sel:[0,0,0] op_sel_hi:[0,1,1]" \
        : "+v"(ac) : "v"(fv), "v"(xv));
// acc.h[ch] += fv.HI * xv.h[ch]  (filter hi-half broadcast)
#define PKFH(ac, fv, xv) \
    asm("v_pk_fma_f16 %0, %1, %2, %0 op_sel:[1,0,0] op_sel_hi:[1,1,1]" \
        : "+v"(ac) : "v"(fv), "v"(xv));

// filter row (taps T..T+4) vs 8 window uints qa.x..qb.w (pixel 4s..4s+7,
// channel-pair packed). Col k tap j reads uint (k+j). Accs A0..A3 per col.
#define ROW8(T, qa, qb, A0, A1, A2, A3) \
  PKFL(A0, frA[T+0], qa.x) PKFH(A1, frA[T+0], qa.y) PKFL(A2, frB[T+0], qa.z) PKFH(A3, frB[T+0], qa.w) \
  PKFL(A0, frA[T+1], qa.y) PKFH(A1, frA[T+1], qa.z) PKFL(A2, frB[T+1], qa.w) PKFH(A3, frB[T+1], qb.x) \
  PKFL(A0, frA[T+2], qa.z) PKFH(A1, frA[T+2], qa.w) PKFL(A2, frB[T+2], qb.x) PKFH(A3, frB[T+2], qb.y) \
  PKFL(A0, frA[T+3], qa.w) PKFH(A1, frA[T+3], qb.x) PKFL(A2, frB[T+3], qb.y) PKFH(A3, frB[T+3], qb.z) \
  PKFL(A0, frA[T+4], qb.x) PKFH(A1, frA[T+4], qb.y) PKFL(A2, frB[T+4], qb.z) PKFH(A3, frB[T+4], qb.w)

// One pass (5 rows from ROWBASE) over channel-pair-packed BUF; outputs 4
// packed col results S0..S3 (each = (ch_c, ch_c1) f16).
#define PASS2(BUF, ROWBASE, S0, S1, S2, S3) { \
    unsigned e0=0u,e1=0u,e2=0u,e3=0u,o0=0u,o1=0u,o2=0u,o3=0u; \
    _Pragma("unroll") \
    for (int i = 0; i < 5; ++i) { \
        const int b = ((ROWBASE) + i) * USH + 4 * s; \
        uint4 qa = *(const uint4*)&(BUF)[b]; \
        uint4 qb = *(const uint4*)&(BUF)[b + 4]; \
        if (i & 1) { ROW8(5*i, qa, qb, o0, o1, o2, o3) } \
        else       { ROW8(5*i, qa, qb, e0, e1, e2, e3) } \
    } \
    asm("v_pk_add_f16 %0, %1, %2" : "=v"(S0) : "v"(e0), "v"(o0)); \
    asm("v_pk_add_f16 %0, %1, %2" : "=v"(S1) : "v"(e1), "v"(o1)); \
    asm("v_pk_add_f16 %0, %1, %2" : "=v"(S2) : "v"(e2), "v"(o2)); \
    asm("v_pk_add_f16 %0, %1, %2" : "=v"(S3) : "v"(e3), "v"(o3)); }

// lgkm-only barrier: LDS ordered, global prefetch loads stay in flight
#define LBAR() { asm volatile("s_waitcnt lgkmcnt(0)" ::: "memory"); \
                 __builtin_amdgcn_s_barrier(); asm volatile("" ::: "memory"); }

#define PACK4(pa, pb) make_uint4(pkh(pa.x, pb.x), pkh(pa.y, pb.y), \
                                 pkh(pa.z, pb.z), pkh(pa.w, pb.w))

// store packed-pair results: channels at P and P+HW
#define STORES(P, S0, S1, S2, S3) { \
    union { unsigned u; h2v h; } U0, U1, U2, U3; \
    U0.u = S0; U1.u = S1; U2.u = S2; U3.u = S3; \
    float* oq_ = (P) + HW; \
    if (s >= 1 && gwb + 1 < W) { \
        *(float2*)(P)  = make_float2((float)U0.h.x, (float)U1.h.x); \
        *(float2*)oq_  = make_float2((float)U0.h.y, (float)U1.h.y); \
    } \
    if (s <= 14 && gwb + 3 < W) { \
        *(float2*)((P) + 2) = make_float2((float)U2.h.x, (float)U3.h.x); \
        *(float2*)(oq_ + 2) = make_float2((float)U2.h.y, (float)U3.h.y); \
    } }

// 4 channels CB..CB+3: pairs in Ra,Rb; prefetch pairs (CB+4,5)->La after
// bar1, (CB+6,7)->Lb before bar2.
#define QBODY(CB, Ra, Rb, La, Lb) { \
    float4 a0a=z4, a0b=z4, a1a=z4, a1b=z4; \
    const bool pfA = (CB) + 4 < CPB; \
    if (pfA) { \
        if (ok0) { a0a = *(const float4*)pfp0; a0b = *(const float4*)(pfp0 + HW); } \
        if (ok1) { a1a = *(const float4*)pfp1; a1b = *(const float4*)(pfp1 + HW); } \
    } \
    unsigned t0, t1, t2, t3, u0, u1, u2, u3; \
    PASS2(Ra, r, t0, t1, t2, t3) \
    PASS2(Rb, r, u0, u1, u2, u3) \
    *(uint2*)&stA[r * USH + 2 + 4 * s] = make_uint2(t0, t1); \
    *(uint2*)&stA[r * USH + 4 + 4 * s] = make_uint2(t2, t3); \
    *(uint2*)&stB[r * USH + 2 + 4 * s] = make_uint2(u0, u1); \
    *(uint2*)&stB[r * USH + 4 + 4 * s] = make_uint2(u2, u3); \
    LBAR(); \
    if (pfA) { \
        *(uint4*)&(La)[l0u] = PACK4(a0a, a0b); \
        if (has1) *(uint4*)&(La)[l1u] = PACK4(a1a, a1b); \
    } \
    float4 b0a=z4, b0b=z4, b1a=z4, b1b=z4; \
    const bool pfB = (CB) + 6 < CPB; \
    if (pfB) { \
        if (ok0) { b0a = *(const float4*)(pfp0 + 2 * (size_t)HW); \
                   b0b = *(const float4*)(pfp0 + 3 * (size_t)HW); } \
        if (ok1) { b1a = *(const float4*)(pfp1 + 2 * (size_t)HW); \
                   b1b = *(const float4*)(pfp1 + 3 * (size_t)HW); } \
    } \
    PASS2(stA, rc - 2, t0, t1, t2, t3) \
    PASS2(stB, rc - 2, u0, u1, u2, u3) \
    if (prow) { \
        STORES(op, t0, t1, t2, t3) \
        STORES(op + 2 * (size_t)HW, u0, u1, u2, u3) \
    } \
    if (pfB) { \
        *(uint4*)&(Lb)[l0u] = PACK4(b0a, b0b); \
        if (has1) *(uint4*)&(Lb)[l1u] = PACK4(b1a, b1b); \
    } \
    LBAR(); \
    pfp0 += 4 * (size_t)HW; pfp1 += 4 * (size_t)HW; \
    op += 4 * (size_t)HW; \
}

__global__ __launch_bounds__(256)
void lga2_fused(const float* __restrict__ x, const float* __restrict__ f,
                float* __restrict__ out, int N, int C, int H, int W, int CPB) {
    const int tid = threadIdx.x;
    const int r = tid >> 4;            // temp-region row 0..15
    const int s = tid & 15;            // quad-strip 0..15
    const int oh0 = blockIdx.y * OH;
    const int ow0 = blockIdx.x * OW;
    const int CG = C / CPB;
    const int n  = blockIdx.z / CG;
    const int c0 = (blockIdx.z % CG) * CPB;
    const int HW = H * W;

    __shared__ unsigned sxA[20 * USH], sxB[20 * USH];
    __shared__ unsigned sxC[20 * USH], sxD[20 * USH];
    __shared__ unsigned stA[16 * USH], stB[16 * USH];

    // zero temp guard uints 0,1,66,67 per row, both st buffers
    if (tid < 128) {
        unsigned* stz = (tid < 64) ? stA : stB;
        int i = tid & 63, row = i >> 2, q = i & 3;
        stz[row * USH + (q < 2 ? q : q + 64)] = 0u;
    }

    // ---- filter registers: 25 taps x 2 packed (col pairs), proven layout ----
    const int gh_f = oh0 - 2 + r;
    const int gwb  = ow0 - 2 + 4 * s;
    const bool rowok = (gh_f >= 0) && (gh_f < H);
    const bool p0ok = rowok && (gwb >= 0) && (gwb + 1 < W);
    const bool p1ok = rowok && (gwb + 3 < W);
    const float* fb = f + (size_t)(n * 25) * HW + (size_t)(rowok ? gh_f : 0) * W;

    unsigned frA[25], frB[25];
    #pragma unroll
    for (int t = 0; t < 25; ++t) {
        float2 v01 = p0ok ? *(const float2*)(fb + (size_t)t * HW + gwb)
                          : make_float2(0.f, 0.f);
        float2 v23 = p1ok ? *(const float2*)(fb + (size_t)t * HW + gwb + 2)
                          : make_float2(0.f, 0.f);
        frA[t] = pkh(v01.x, v01.y);
        frB[t] = pkh(v23.x, v23.y);
        if (t == 12) __builtin_amdgcn_sched_barrier(0);  // 2 load batches
    }
    #pragma unroll
    for (int t = 0; t < 25; ++t)
        asm volatile("" : "+v"(frA[t]), "+v"(frB[t]));   // pin packed filters

    // ---- staging: 340 quads (20 rows x 17 x 4 pixels), b128 per quad ----
    const int i1 = tid + 256;
    const bool has1 = (tid < 340 - 256);
    const int row0 = tid / 17, v0 = tid - row0 * 17;
    const int row1 = i1 / 17,  v1 = i1 - row1 * 17;
    const int g0h = oh0 - 4 + row0, g0c = ow0 - 4 + 4 * v0;
    const int g1h = oh0 - 4 + row1, g1c = ow0 - 4 + 4 * v1;
    const bool ok0 = (g0h >= 0) && (g0h < H) && (g0c >= 0) && (g0c + 3 < W);
    const bool ok1 = has1 && (g1h >= 0) && (g1h < H) && (g1c >= 0) && (g1c + 3 < W);
    const int off0 = ok0 ? (g0h * W + g0c) : 0;
    const int off1 = ok1 ? (g1h * W + g1c) : 0;
    const int l0u = row0 * USH + 4 * v0;   // b128-aligned
    const int l1u = row1 * USH + 4 * v1;

    const float4 z4 = make_float4(0.f, 0.f, 0.f, 0.f);
    const float* xc = x + (size_t)(n * C + c0) * HW;

    {   // prologue: stage pair (0,1) -> sxA, pair (2,3) -> sxB
        float4 pa = ok0 ? *(const float4*)(xc + off0) : z4;
        float4 pb = ok0 ? *(const float4*)(xc + HW + off0) : z4;
        *(uint4*)&sxA[l0u] = PACK4(pa, pb);
        float4 pc = ok0 ? *(const float4*)(xc + 2 * (size_t)HW + off0) : z4;
        float4 pd = ok0 ? *(const float4*)(xc + 3 * (size_t)HW + off0) : z4;
        *(uint4*)&sxB[l0u] = PACK4(pc, pd);
        if (has1) {
            float4 qa = ok1 ? *(const float4*)(xc + off1) : z4;
            float4 qb = ok1 ? *(const float4*)(xc + HW + off1) : z4;
            *(uint4*)&sxA[l1u] = PACK4(qa, qb);
            float4 qc = ok1 ? *(const float4*)(xc + 2 * (size_t)HW + off1) : z4;
            float4 qd = ok1 ? *(const float4*)(xc + 3 * (size_t)HW + off1) : z4;
            *(uint4*)&sxB[l1u] = PACK4(qc, qd);
        }
    }
    __syncthreads();

    const bool prow = (r >= 2) && (r <= 13) && (gh_f < H);
    const int rc = (r < 2) ? 2 : ((r > 13) ? 13 : r);
    float* op = out + ((size_t)(n * C + c0) * H + gh_f) * W + gwb;
    const float* pfp0 = xc + 4 * (size_t)HW + off0;
    const float* pfp1 = xc + 4 * (size_t)HW + off1;

    for (int cq = 0; cq < CPB; cq += 8) {
        QBODY(cq,     sxA, sxB, sxC, sxD)
        QBODY(cq + 4, sxC, sxD, sxA, sxB)
    }
}

extern "C" void kernel_launch(void* const* d_in, const int* in_sizes, int n_in,
                              void* d_out, int out_size, void* d_ws, size_t ws_size,
                              hipStream_t stream) {
    const float* x = (const float*)d_in[0];
    const float* f = (const float*)d_in[1];
    float* out = (float*)d_out;

    const int N = 2, C = 64, H = 256, W = 512;
    const int CPB = 8;                         // 8 channel groups
    const int CG = C / CPB;

    dim3 grid((W + OW - 1) / OW,               // 9
              (H + OH - 1) / OH,               // 22
              N * CG);                         // 16  -> 3168 blocks of 256 thr
    lga2_fused<<<grid, 256, 0, stream>>>(x, f, out, N, C, H, W, CPB);
}

// Round 26
// 68.536 us; speedup vs baseline: 1.4088x; 1.4088x over previous
//
#include <hip/hip_runtime.h>
#include <hip/hip_fp16.h>

// LGA2 fused: out = LGA(LGA(x,f),f), radius=2 (25 taps), fp32 in/out.
// x: [N=2, C=64, H=256, W=512], f: [N, 25, H, W], out like x.
//
// R26 = R24 verbatim (session best, 68.6us) - reverting R25's CPB=8
// (filter-traffic x4 cost +147MB FETCH >> any load-balance gain).
//
// Structure: channel-pair packing (f16 halves = same pixel, chans c/c+1),
// op_sel filter broadcast, 4 channels (2 pairs) per phase with two
// independent PASS2 chains, 2 lgkm barriers per 4 channels, staggered
// 4-buffer prefetch rotation. LDS 34KB -> 4 blocks/CU -> 128-VGPR budget
// (filters resident, VGPR=84). Tile: temp 16x64, out 12x60, x 20x68.

typedef __fp16 h2v __attribute__((ext_vector_type(2)));

#define OH 12
#define OW 60
#define USH 76

__device__ __forceinline__ unsigned pkh(float a, float b) {
    union { h2v h; unsigned u; } c;
    c.h = __builtin_amdgcn_cvt_pkrtz(a, b);
    return c.u;
}

// acc.h[ch] += fv.LO * xv.h[ch]  (filter lo-half broadcast to both channels)
#define PKFL(ac, fv, xv) \
    asm("v_pk_fma_f16 %0, %1, %2, %0 op_sel:[0,0,0] op_sel_hi:[0,1,1]" \
        : "+v"(ac) : "v"(fv), "v"(xv));
// acc.h[ch] += fv.HI * xv.h[ch]  (filter hi-half broadcast)
#define PKFH(ac, fv, xv) \
    asm("v_pk_fma_f16 %0, %1, %2, %0 op_sel:[1,0,0] op_sel_hi:[1,1,1]" \
        : "+v"(ac) : "v"(fv), "v"(xv));

// filter row (taps T..T+4) vs 8 window uints qa.x..qb.w (pixel 4s..4s+7,
// channel-pair packed). Col k tap j reads uint (k+j). Accs A0..A3 per col.
#define ROW8(T, qa, qb, A0, A1, A2, A3) \
  PKFL(A0, frA[T+0], qa.x) PKFH(A1, frA[T+0], qa.y) PKFL(A2, frB[T+0], qa.z) PKFH(A3, frB[T+0], qa.w) \
  PKFL(A0, frA[T+1], qa.y) PKFH(A1, frA[T+1], qa.z) PKFL(A2, frB[T+1], qa.w) PKFH(A3, frB[T+1], qb.x) \
  PKFL(A0, frA[T+2], qa.z) PKFH(A1, frA[T+2], qa.w) PKFL(A2, frB[T+2], qb.x) PKFH(A3, frB[T+2], qb.y) \
  PKFL(A0, frA[T+3], qa.w) PKFH(A1, frA[T+3], qb.x) PKFL(A2, frB[T+3], qb.y) PKFH(A3, frB[T+3], qb.z) \
  PKFL(A0, frA[T+4], qb.x) PKFH(A1, frA[T+4], qb.y) PKFL(A2, frB[T+4], qb.z) PKFH(A3, frB[T+4], qb.w)

// One pass (5 rows from ROWBASE) over channel-pair-packed BUF; outputs 4
// packed col results S0..S3 (each = (ch_c, ch_c1) f16).
#define PASS2(BUF, ROWBASE, S0, S1, S2, S3) { \
    unsigned e0=0u,e1=0u,e2=0u,e3=0u,o0=0u,o1=0u,o2=0u,o3=0u; \
    _Pragma("unroll") \
    for (int i = 0; i < 5; ++i) { \
        const int b = ((ROWBASE) + i) * USH + 4 * s; \
        uint4 qa = *(const uint4*)&(BUF)[b]; \
        uint4 qb = *(const uint4*)&(BUF)[b + 4]; \
        if (i & 1) { ROW8(5*i, qa, qb, o0, o1, o2, o3) } \
        else       { ROW8(5*i, qa, qb, e0, e1, e2, e3) } \
    } \
    asm("v_pk_add_f16 %0, %1, %2" : "=v"(S0) : "v"(e0), "v"(o0)); \
    asm("v_pk_add_f16 %0, %1, %2" : "=v"(S1) : "v"(e1), "v"(o1)); \
    asm("v_pk_add_f16 %0, %1, %2" : "=v"(S2) : "v"(e2), "v"(o2)); \
    asm("v_pk_add_f16 %0, %1, %2" : "=v"(S3) : "v"(e3), "v"(o3)); }

// lgkm-only barrier: LDS ordered, global prefetch loads stay in flight
#define LBAR() { asm volatile("s_waitcnt lgkmcnt(0)" ::: "memory"); \
                 __builtin_amdgcn_s_barrier(); asm volatile("" ::: "memory"); }

#define PACK4(pa, pb) make_uint4(pkh(pa.x, pb.x), pkh(pa.y, pb.y), \
                                 pkh(pa.z, pb.z), pkh(pa.w, pb.w))

// store packed-pair results: channels at P and P+HW
#define STORES(P, S0, S1, S2, S3) { \
    union { unsigned u; h2v h; } U0, U1, U2, U3; \
    U0.u = S0; U1.u = S1; U2.u = S2; U3.u = S3; \
    float* oq_ = (P) + HW; \
    if (s >= 1 && gwb + 1 < W) { \
        *(float2*)(P)  = make_float2((float)U0.h.x, (float)U1.h.x); \
        *(float2*)oq_  = make_float2((float)U0.h.y, (float)U1.h.y); \
    } \
    if (s <= 14 && gwb + 3 < W) { \
        *(float2*)((P) + 2) = make_float2((float)U2.h.x, (float)U3.h.x); \
        *(float2*)(oq_ + 2) = make_float2((float)U2.h.y, (float)U3.h.y); \
    } }

// 4 channels CB..CB+3: pairs in Ra,Rb; prefetch pairs (CB+4,5)->La after
// bar1, (CB+6,7)->Lb before bar2.
#define QBODY(CB, Ra, Rb, La, Lb) { \
    float4 a0a=z4, a0b=z4, a1a=z4, a1b=z4; \
    const bool pfA = (CB) + 4 < CPB; \
    if (pfA) { \
        if (ok0) { a0a = *(const float4*)pfp0; a0b = *(const float4*)(pfp0 + HW); } \
        if (ok1) { a1a = *(const float4*)pfp1; a1b = *(const float4*)(pfp1 + HW); } \
    } \
    unsigned t0, t1, t2, t3, u0, u1, u2, u3; \
    PASS2(Ra, r, t0, t1, t2, t3) \
    PASS2(Rb, r, u0, u1, u2, u3) \
    *(uint2*)&stA[r * USH + 2 + 4 * s] = make_uint2(t0, t1); \
    *(uint2*)&stA[r * USH + 4 + 4 * s] = make_uint2(t2, t3); \
    *(uint2*)&stB[r * USH + 2 + 4 * s] = make_uint2(u0, u1); \
    *(uint2*)&stB[r * USH + 4 + 4 * s] = make_uint2(u2, u3); \
    LBAR(); \
    if (pfA) { \
        *(uint4*)&(La)[l0u] = PACK4(a0a, a0b); \
        if (has1) *(uint4*)&(La)[l1u] = PACK4(a1a, a1b); \
    } \
    float4 b0a=z4, b0b=z4, b1a=z4, b1b=z4; \
    const bool pfB = (CB) + 6 < CPB; \
    if (pfB) { \
        if (ok0) { b0a = *(const float4*)(pfp0 + 2 * (size_t)HW); \
                   b0b = *(const float4*)(pfp0 + 3 * (size_t)HW); } \
        if (ok1) { b1a = *(const float4*)(pfp1 + 2 * (size_t)HW); \
                   b1b = *(const float4*)(pfp1 + 3 * (size_t)HW); } \
    } \
    PASS2(stA, rc - 2, t0, t1, t2, t3) \
    PASS2(stB, rc - 2, u0, u1, u2, u3) \
    if (prow) { \
        STORES(op, t0, t1, t2, t3) \
        STORES(op + 2 * (size_t)HW, u0, u1, u2, u3) \
    } \
    if (pfB) { \
        *(uint4*)&(Lb)[l0u] = PACK4(b0a, b0b); \
        if (has1) *(uint4*)&(Lb)[l1u] = PACK4(b1a, b1b); \
    } \
    LBAR(); \
    pfp0 += 4 * (size_t)HW; pfp1 += 4 * (size_t)HW; \
    op += 4 * (size_t)HW; \
}

__global__ __launch_bounds__(256)
void lga2_fused(const float* __restrict__ x, const float* __restrict__ f,
                float* __restrict__ out, int N, int C, int H, int W, int CPB) {
    const int tid = threadIdx.x;
    const int r = tid >> 4;            // temp-region row 0..15
    const int s = tid & 15;            // quad-strip 0..15
    const int oh0 = blockIdx.y * OH;
    const int ow0 = blockIdx.x * OW;
    const int CG = C / CPB;
    const int n  = blockIdx.z / CG;
    const int c0 = (blockIdx.z % CG) * CPB;
    const int HW = H * W;

    __shared__ unsigned sxA[20 * USH], sxB[20 * USH];
    __shared__ unsigned sxC[20 * USH], sxD[20 * USH];
    __shared__ unsigned stA[16 * USH], stB[16 * USH];

    // zero temp guard uints 0,1,66,67 per row, both st buffers
    if (tid < 128) {
        unsigned* stz = (tid < 64) ? stA : stB;
        int i = tid & 63, row = i >> 2, q = i & 3;
        stz[row * USH + (q < 2 ? q : q + 64)] = 0u;
    }

    // ---- filter registers: 25 taps x 2 packed (col pairs), proven layout ----
    const int gh_f = oh0 - 2 + r;
    const int gwb  = ow0 - 2 + 4 * s;
    const bool rowok = (gh_f >= 0) && (gh_f < H);
    const bool p0ok = rowok && (gwb >= 0) && (gwb + 1 < W);
    const bool p1ok = rowok && (gwb + 3 < W);
    const float* fb = f + (size_t)(n * 25) * HW + (size_t)(rowok ? gh_f : 0) * W;

    unsigned frA[25], frB[25];
    #pragma unroll
    for (int t = 0; t < 25; ++t) {
        float2 v01 = p0ok ? *(const float2*)(fb + (size_t)t * HW + gwb)
                          : make_float2(0.f, 0.f);
        float2 v23 = p1ok ? *(const float2*)(fb + (size_t)t * HW + gwb + 2)
                          : make_float2(0.f, 0.f);
        frA[t] = pkh(v01.x, v01.y);
        frB[t] = pkh(v23.x, v23.y);
        if (t == 12) __builtin_amdgcn_sched_barrier(0);  // 2 load batches
    }
    #pragma unroll
    for (int t = 0; t < 25; ++t)
        asm volatile("" : "+v"(frA[t]), "+v"(frB[t]));   // pin packed filters

    // ---- staging: 340 quads (20 rows x 17 x 4 pixels), b128 per quad ----
    const int i1 = tid + 256;
    const bool has1 = (tid < 340 - 256);
    const int row0 = tid / 17, v0 = tid - row0 * 17;
    const int row1 = i1 / 17,  v1 = i1 - row1 * 17;
    const int g0h = oh0 - 4 + row0, g0c = ow0 - 4 + 4 * v0;
    const int g1h = oh0 - 4 + row1, g1c = ow0 - 4 + 4 * v1;
    const bool ok0 = (g0h >= 0) && (g0h < H) && (g0c >= 0) && (g0c + 3 < W);
    const bool ok1 = has1 && (g1h >= 0) && (g1h < H) && (g1c >= 0) && (g1c + 3 < W);
    const int off0 = ok0 ? (g0h * W + g0c) : 0;
    const int off1 = ok1 ? (g1h * W + g1c) : 0;
    const int l0u = row0 * USH + 4 * v0;   // b128-aligned
    const int l1u = row1 * USH + 4 * v1;

    const float4 z4 = make_float4(0.f, 0.f, 0.f, 0.f);
    const float* xc = x + (size_t)(n * C + c0) * HW;

    {   // prologue: stage pair (0,1) -> sxA, pair (2,3) -> sxB
        float4 pa = ok0 ? *(const float4*)(xc + off0) : z4;
        float4 pb = ok0 ? *(const float4*)(xc + HW + off0) : z4;
        *(uint4*)&sxA[l0u] = PACK4(pa, pb);
        float4 pc = ok0 ? *(const float4*)(xc + 2 * (size_t)HW + off0) : z4;
        float4 pd = ok0 ? *(const float4*)(xc + 3 * (size_t)HW + off0) : z4;
        *(uint4*)&sxB[l0u] = PACK4(pc, pd);
        if (has1) {
            float4 qa = ok1 ? *(const float4*)(xc + off1) : z4;
            float4 qb = ok1 ? *(const float4*)(xc + HW + off1) : z4;
            *(uint4*)&sxA[l1u] = PACK4(qa, qb);
            float4 qc = ok1 ? *(const float4*)(xc + 2 * (size_t)HW + off1) : z4;
            float4 qd = ok1 ? *(const float4*)(xc + 3 * (size_t)HW + off1) : z4;
            *(uint4*)&sxB[l1u] = PACK4(qc, qd);
        }
    }
    __syncthreads();

    const bool prow = (r >= 2) && (r <= 13) && (gh_f < H);
    const int rc = (r < 2) ? 2 : ((r > 13) ? 13 : r);
    float* op = out + ((size_t)(n * C + c0) * H + gh_f) * W + gwb;
    const float* pfp0 = xc + 4 * (size_t)HW + off0;
    const float* pfp1 = xc + 4 * (size_t)HW + off1;

    for (int cq = 0; cq < CPB; cq += 8) {
        QBODY(cq,     sxA, sxB, sxC, sxD)
        QBODY(cq + 4, sxC, sxD, sxA, sxB)
    }
}

extern "C" void kernel_launch(void* const* d_in, const int* in_sizes, int n_in,
                              void* d_out, int out_size, void* d_ws, size_t ws_size,
                              hipStream_t stream) {
    const float* x = (const float*)d_in[0];
    const float* f = (const float*)d_in[1];
    float* out = (float*)d_out;

    const int N = 2, C = 64, H = 256, W = 512;
    const int CPB = 32;                        // 2 channel groups
    const int CG = C / CPB;

    dim3 grid((W + OW - 1) / OW,               // 9
              (H + OH - 1) / OH,               // 22
              N * CG);                         // 4  -> 792 blocks of 256 thr
    lga2_fused<<<grid, 256, 0, stream>>>(x, f, out, N, C, H, W, CPB);
}

// Round 27
// 68.171 us; speedup vs baseline: 1.4163x; 1.0053x over previous
//
#include <hip/hip_runtime.h>
#include <hip/hip_fp16.h>

// LGA2 fused: out = LGA(LGA(x,f),f), radius=2 (25 taps), fp32 in/out.
// x: [N=2, C=64, H=256, W=512], f: [N, 25, H, W], out like x.
//
// R27 = R26/R24 (68.5us, session best) with ONE change: USH 76 -> 72.
// Targeting SQ_LDS_BANK_CONFLICT 4.17M cy (vs 0.87M in the b64/USH=40
// structure): 76 mod 32 = 12 puts the wave's 4 rows at bank offsets
// {0,12,24,4} colliding same-bank/different-address on b128 reads.
// 72 mod 32 = 8 -> bank-quad (s+2r) mod 8, cleaner 8-per-quad partition.
// Rows still 16B-aligned (72%4==0), content 68 uints <= 72. Side effect:
// LDS 34.3->32.3KB -> cap 5 blocks/CU (VGPR budget ~102 > 84 needed).
//
// Structure (R24): channel-pair packing (f16 halves = same pixel, chans
// c/c+1), op_sel filter broadcast, 4 channels (2 pairs) per phase with two
// independent PASS2 chains, 2 lgkm barriers per 4 channels, staggered
// 4-buffer prefetch rotation. Tile: temp 16x64, out 12x60, x 20x68.

typedef __fp16 h2v __attribute__((ext_vector_type(2)));

#define OH 12
#define OW 60
#define USH 72

__device__ __forceinline__ unsigned pkh(float a, float b) {
    union { h2v h; unsigned u; } c;
    c.h = __builtin_amdgcn_cvt_pkrtz(a, b);
    return c.u;
}

// acc.h[ch] += fv.LO * xv.h[ch]  (filter lo-half broadcast to both channels)
#define PKFL(ac, fv, xv) \
    asm("v_pk_fma_f16 %0, %1, %2, %0 op_sel:[0,0,0] op_sel_hi:[0,1,1]" \
        : "+v"(ac) : "v"(fv), "v"(xv));
// acc.h[ch] += fv.HI * xv.h[ch]  (filter hi-half broadcast)
#define PKFH(ac, fv, xv) \
    asm("v_pk_fma_f16 %0, %1, %2, %0 op_sel:[1,0,0] op_sel_hi:[1,1,1]" \
        : "+v"(ac) : "v"(fv), "v"(xv));

// filter row (taps T..T+4) vs 8 window uints qa.x..qb.w (pixel 4s..4s+7,
// channel-pair packed). Col k tap j reads uint (k+j). Accs A0..A3 per col.
#define ROW8(T, qa, qb, A0, A1, A2, A3) \
  PKFL(A0, frA[T+0], qa.x) PKFH(A1, frA[T+0], qa.y) PKFL(A2, frB[T+0], qa.z) PKFH(A3, frB[T+0], qa.w) \
  PKFL(A0, frA[T+1], qa.y) PKFH(A1, frA[T+1], qa.z) PKFL(A2, frB[T+1], qa.w) PKFH(A3, frB[T+1], qb.x) \
  PKFL(A0, frA[T+2], qa.z) PKFH(A1, frA[T+2], qa.w) PKFL(A2, frB[T+2], qb.x) PKFH(A3, frB[T+2], qb.y) \
  PKFL(A0, frA[T+3], qa.w) PKFH(A1, frA[T+3], qb.x) PKFL(A2, frB[T+3], qb.y) PKFH(A3, frB[T+3], qb.z) \
  PKFL(A0, frA[T+4], qb.x) PKFH(A1, frA[T+4], qb.y) PKFL(A2, frB[T+4], qb.z) PKFH(A3, frB[T+4], qb.w)

// One pass (5 rows from ROWBASE) over channel-pair-packed BUF; outputs 4
// packed col results S0..S3 (each = (ch_c, ch_c1) f16).
#define PASS2(BUF, ROWBASE, S0, S1, S2, S3) { \
    unsigned e0=0u,e1=0u,e2=0u,e3=0u,o0=0u,o1=0u,o2=0u,o3=0u; \
    _Pragma("unroll") \
    for (int i = 0; i < 5; ++i) { \
        const int b = ((ROWBASE) + i) * USH + 4 * s; \
        uint4 qa = *(const uint4*)&(BUF)[b]; \
        uint4 qb = *(const uint4*)&(BUF)[b + 4]; \
        if (i & 1) { ROW8(5*i, qa, qb, o0, o1, o2, o3) } \
        else       { ROW8(5*i, qa, qb, e0, e1, e2, e3) } \
    } \
    asm("v_pk_add_f16 %0, %1, %2" : "=v"(S0) : "v"(e0), "v"(o0)); \
    asm("v_pk_add_f16 %0, %1, %2" : "=v"(S1) : "v"(e1), "v"(o1)); \
    asm("v_pk_add_f16 %0, %1, %2" : "=v"(S2) : "v"(e2), "v"(o2)); \
    asm("v_pk_add_f16 %0, %1, %2" : "=v"(S3) : "v"(e3), "v"(o3)); }

// lgkm-only barrier: LDS ordered, global prefetch loads stay in flight
#define LBAR() { asm volatile("s_waitcnt lgkmcnt(0)" ::: "memory"); \
                 __builtin_amdgcn_s_barrier(); asm volatile("" ::: "memory"); }

#define PACK4(pa, pb) make_uint4(pkh(pa.x, pb.x), pkh(pa.y, pb.y), \
                                 pkh(pa.z, pb.z), pkh(pa.w, pb.w))

// store packed-pair results: channels at P and P+HW
#define STORES(P, S0, S1, S2, S3) { \
    union { unsigned u; h2v h; } U0, U1, U2, U3; \
    U0.u = S0; U1.u = S1; U2.u = S2; U3.u = S3; \
    float* oq_ = (P) + HW; \
    if (s >= 1 && gwb + 1 < W) { \
        *(float2*)(P)  = make_float2((float)U0.h.x, (float)U1.h.x); \
        *(float2*)oq_  = make_float2((float)U0.h.y, (float)U1.h.y); \
    } \
    if (s <= 14 && gwb + 3 < W) { \
        *(float2*)((P) + 2) = make_float2((float)U2.h.x, (float)U3.h.x); \
        *(float2*)(oq_ + 2) = make_float2((float)U2.h.y, (float)U3.h.y); \
    } }

// 4 channels CB..CB+3: pairs in Ra,Rb; prefetch pairs (CB+4,5)->La after
// bar1, (CB+6,7)->Lb before bar2.
#define QBODY(CB, Ra, Rb, La, Lb) { \
    float4 a0a=z4, a0b=z4, a1a=z4, a1b=z4; \
    const bool pfA = (CB) + 4 < CPB; \
    if (pfA) { \
        if (ok0) { a0a = *(const float4*)pfp0; a0b = *(const float4*)(pfp0 + HW); } \
        if (ok1) { a1a = *(const float4*)pfp1; a1b = *(const float4*)(pfp1 + HW); } \
    } \
    unsigned t0, t1, t2, t3, u0, u1, u2, u3; \
    PASS2(Ra, r, t0, t1, t2, t3) \
    PASS2(Rb, r, u0, u1, u2, u3) \
    *(uint2*)&stA[r * USH + 2 + 4 * s] = make_uint2(t0, t1); \
    *(uint2*)&stA[r * USH + 4 + 4 * s] = make_uint2(t2, t3); \
    *(uint2*)&stB[r * USH + 2 + 4 * s] = make_uint2(u0, u1); \
    *(uint2*)&stB[r * USH + 4 + 4 * s] = make_uint2(u2, u3); \
    LBAR(); \
    if (pfA) { \
        *(uint4*)&(La)[l0u] = PACK4(a0a, a0b); \
        if (has1) *(uint4*)&(La)[l1u] = PACK4(a1a, a1b); \
    } \
    float4 b0a=z4, b0b=z4, b1a=z4, b1b=z4; \
    const bool pfB = (CB) + 6 < CPB; \
    if (pfB) { \
        if (ok0) { b0a = *(const float4*)(pfp0 + 2 * (size_t)HW); \
                   b0b = *(const float4*)(pfp0 + 3 * (size_t)HW); } \
        if (ok1) { b1a = *(const float4*)(pfp1 + 2 * (size_t)HW); \
                   b1b = *(const float4*)(pfp1 + 3 * (size_t)HW); } \
    } \
    PASS2(stA, rc - 2, t0, t1, t2, t3) \
    PASS2(stB, rc - 2, u0, u1, u2, u3) \
    if (prow) { \
        STORES(op, t0, t1, t2, t3) \
        STORES(op + 2 * (size_t)HW, u0, u1, u2, u3) \
    } \
    if (pfB) { \
        *(uint4*)&(Lb)[l0u] = PACK4(b0a, b0b); \
        if (has1) *(uint4*)&(Lb)[l1u] = PACK4(b1a, b1b); \
    } \
    LBAR(); \
    pfp0 += 4 * (size_t)HW; pfp1 += 4 * (size_t)HW; \
    op += 4 * (size_t)HW; \
}

__global__ __launch_bounds__(256)
void lga2_fused(const float* __restrict__ x, const float* __restrict__ f,
                float* __restrict__ out, int N, int C, int H, int W, int CPB) {
    const int tid = threadIdx.x;
    const int r = tid >> 4;            // temp-region row 0..15
    const int s = tid & 15;            // quad-strip 0..15
    const int oh0 = blockIdx.y * OH;
    const int ow0 = blockIdx.x * OW;
    const int CG = C / CPB;
    const int n  = blockIdx.z / CG;
    const int c0 = (blockIdx.z % CG) * CPB;
    const int HW = H * W;

    __shared__ unsigned sxA[20 * USH], sxB[20 * USH];
    __shared__ unsigned sxC[20 * USH], sxD[20 * USH];
    __shared__ unsigned stA[16 * USH], stB[16 * USH];

    // zero temp guard uints 0,1,66,67 per row, both st buffers
    if (tid < 128) {
        unsigned* stz = (tid < 64) ? stA : stB;
        int i = tid & 63, row = i >> 2, q = i & 3;
        stz[row * USH + (q < 2 ? q : q + 64)] = 0u;
    }

    // ---- filter registers: 25 taps x 2 packed (col pairs), proven layout ----
    const int gh_f = oh0 - 2 + r;
    const int gwb  = ow0 - 2 + 4 * s;
    const bool rowok = (gh_f >= 0) && (gh_f < H);
    const bool p0ok = rowok && (gwb >= 0) && (gwb + 1 < W);
    const bool p1ok = rowok && (gwb + 3 < W);
    const float* fb = f + (size_t)(n * 25) * HW + (size_t)(rowok ? gh_f : 0) * W;

    unsigned frA[25], frB[25];
    #pragma unroll
    for (int t = 0; t < 25; ++t) {
        float2 v01 = p0ok ? *(const float2*)(fb + (size_t)t * HW + gwb)
                          : make_float2(0.f, 0.f);
        float2 v23 = p1ok ? *(const float2*)(fb + (size_t)t * HW + gwb + 2)
                          : make_float2(0.f, 0.f);
        frA[t] = pkh(v01.x, v01.y);
        frB[t] = pkh(v23.x, v23.y);
        if (t == 12) __builtin_amdgcn_sched_barrier(0);  // 2 load batches
    }
    #pragma unroll
    for (int t = 0; t < 25; ++t)
        asm volatile("" : "+v"(frA[t]), "+v"(frB[t]));   // pin packed filters

    // ---- staging: 340 quads (20 rows x 17 x 4 pixels), b128 per quad ----
    const int i1 = tid + 256;
    const bool has1 = (tid < 340 - 256);
    const int row0 = tid / 17, v0 = tid - row0 * 17;
    const int row1 = i1 / 17,  v1 = i1 - row1 * 17;
    const int g0h = oh0 - 4 + row0, g0c = ow0 - 4 + 4 * v0;
    const int g1h = oh0 - 4 + row1, g1c = ow0 - 4 + 4 * v1;
    const bool ok0 = (g0h >= 0) && (g0h < H) && (g0c >= 0) && (g0c + 3 < W);
    const bool ok1 = has1 && (g1h >= 0) && (g1h < H) && (g1c >= 0) && (g1c + 3 < W);
    const int off0 = ok0 ? (g0h * W + g0c) : 0;
    const int off1 = ok1 ? (g1h * W + g1c) : 0;
    const int l0u = row0 * USH + 4 * v0;   // b128-aligned
    const int l1u = row1 * USH + 4 * v1;

    const float4 z4 = make_float4(0.f, 0.f, 0.f, 0.f);
    const float* xc = x + (size_t)(n * C + c0) * HW;

    {   // prologue: stage pair (0,1) -> sxA, pair (2,3) -> sxB
        float4 pa = ok0 ? *(const float4*)(xc + off0) : z4;
        float4 pb = ok0 ? *(const float4*)(xc + HW + off0) : z4;
        *(uint4*)&sxA[l0u] = PACK4(pa, pb);
        float4 pc = ok0 ? *(const float4*)(xc + 2 * (size_t)HW + off0) : z4;
        float4 pd = ok0 ? *(const float4*)(xc + 3 * (size_t)HW + off0) : z4;
        *(uint4*)&sxB[l0u] = PACK4(pc, pd);
        if (has1) {
            float4 qa = ok1 ? *(const float4*)(xc + off1) : z4;
            float4 qb = ok1 ? *(const float4*)(xc + HW + off1) : z4;
            *(uint4*)&sxA[l1u] = PACK4(qa, qb);
            float4 qc = ok1 ? *(const float4*)(xc + 2 * (size_t)HW + off1) : z4;
            float4 qd = ok1 ? *(const float4*)(xc + 3 * (size_t)HW + off1) : z4;
            *(uint4*)&sxB[l1u] = PACK4(qc, qd);
        }
    }
    __syncthreads();

    const bool prow = (r >= 2) && (r <= 13) && (gh_f < H);
    const int rc = (r < 2) ? 2 : ((r > 13) ? 13 : r);
    float* op = out + ((size_t)(n * C + c0) * H + gh_f) * W + gwb;
    const float* pfp0 = xc + 4 * (size_t)HW + off0;
    const float* pfp1 = xc + 4 * (size_t)HW + off1;

    for (int cq = 0; cq < CPB; cq += 8) {
        QBODY(cq,     sxA, sxB, sxC, sxD)
        QBODY(cq + 4, sxC, sxD, sxA, sxB)
    }
}

extern "C" void kernel_launch(void* const* d_in, const int* in_sizes, int n_in,
                              void* d_out, int out_size, void* d_ws, size_t ws_size,
                              hipStream_t stream) {
    const float* x = (const float*)d_in[0];
    const float* f = (const float*)d_in[1];
    float* out = (float*)d_out;

    const int N = 2, C = 64, H = 256, W = 512;
    const int CPB = 32;                        // 2 channel groups
    const int CG = C / CPB;

    dim3 grid((W + OW - 1) / OW,               // 9
              (H + OH - 1) / OH,               // 22
              N * CG);                         // 4  -> 792 blocks of 256 thr
    lga2_fused<<<grid, 256, 0, stream>>>(x, f, out, N, C, H, W, CPB);
}